// Round 10
// baseline (1492.142 us; speedup 1.0000x reference)
//
#include <hip/hip_runtime.h>
#include <hip/hip_bf16.h>

// VQ-VAE forward — NHWC bf16 intermediates, MFMA (16x16x32 bf16) for all convs.
// Outputs: [1.25*vq_mse, recon_mse, recon_mse]
//
// MFMA lane layouts (gfx950, HW-verified per guide):
//   A: m = lane&15, k = (lane>>4)*8 + j     (8 bf16 / lane)
//   B: n = lane&15, k = (lane>>4)*8 + j
//   D: n = lane&15, m = (lane>>4)*4 + reg   (4 f32 / lane)
//
// CHANNEL-INTERLEAVED storage: a producer with U=Cc/16 tiles stores tile u,
// column n16 (logical co = u*16+n16) at memory channel m = n16*U+u; consumers
// permute ci in weight prep: logical l(m) = (m%U)*16 + m/U.
//
// dec2+dec3 FUSED (dec23_k): d2 never touches HBM. Block = 4 output rows x
// 64 cols; stage 1 computes the 6x66-px d2 tile (32ch) into 25.5 KB LDS
// (6 blocks/CU -> ~75% occupancy cap for latency hiding); stage 2 runs the
// stride-1 conv (flipped dw3) + fused MSE.
//
// d1p [B][129][129][64]: interior (0,0)..(127,127); pad row/col 128 = 0.

typedef __attribute__((ext_vector_type(8))) short bf16x8;
typedef __attribute__((ext_vector_type(4))) float f32x4;
typedef unsigned short ushort_t;

__device__ __forceinline__ ushort_t f2bf(float v) {
    __hip_bfloat16 h = __float2bfloat16(v);
    return *(ushort_t*)&h;
}
__device__ __forceinline__ float bf2f(ushort_t u) {
    __hip_bfloat16 h = *(__hip_bfloat16*)&u;
    return __bfloat162float(h);
}
__device__ __forceinline__ unsigned pack2r(float a, float b) {   // relu+pack
    return (unsigned)f2bf(fmaxf(a, 0.f)) | ((unsigned)f2bf(fmaxf(b, 0.f)) << 16);
}

// Transformed-weight layout in wbuf (elements of bf16):
//   W1T  @ 0      [co32][k32]            (k=ci*9+kh*3+kw, pad 27->32)
//   W2T  @ 1024   [t9][co64][ci32]       (ci permuted: l2(ci))
//   WD1  @ 19456  [t9][co64][k32]        (k<16 = ci natural, else 0)
//   WD2  @ 37888  [t9][kc2][co32][ci32]  (ci permuted: l4(kc*32+ci))
//   WD3  @ 56320  [t9][co16][ci32]       (taps FLIPPED: src 8-t; ci perm l2; co>=3 -> 0)
//   cn (fp32, 512) @ byte offset 121856

__global__ void zero_k(float* __restrict__ acc) { acc[threadIdx.x] = 0.f; }

__global__ __launch_bounds__(256) void prep_k(
        const float* __restrict__ ew1, const float* __restrict__ ew2,
        const float* __restrict__ dw1, const float* __restrict__ dw2,
        const float* __restrict__ dw3, const float* __restrict__ cb,
        ushort_t* __restrict__ wt, float* __restrict__ cn) {
    int idx = blockIdx.x * 256 + threadIdx.x;
    if (idx < 1024) {
        int co = idx >> 5, k = idx & 31;
        wt[idx] = (k < 27) ? f2bf(ew1[co * 27 + k]) : (ushort_t)0;
    } else if (idx < 19456) {
        int i = idx - 1024;
        int t = i >> 11, co = (i >> 5) & 63, ci = i & 31;
        int lci = ((ci & 1) << 4) | (ci >> 1);                 // l2 (conv1 U=2)
        wt[idx] = f2bf(ew2[co * 288 + lci * 9 + t]);
    } else if (idx < 37888) {
        int i = idx - 19456;
        int t = i >> 11, co = (i >> 5) & 63, k = i & 31;
        wt[idx] = (k < 16) ? f2bf(dw1[k * 576 + co * 9 + t]) : (ushort_t)0;
    } else if (idx < 56320) {
        int i = idx - 37888;
        int t = i >> 11, kc = (i >> 10) & 1, co = (i >> 5) & 31, ci = i & 31;
        int m = kc * 32 + ci;
        int lci = ((m & 3) << 4) | (m >> 2);                   // l4 (dec1 U=4)
        wt[idx] = f2bf(dw2[lci * 288 + co * 9 + t]);
    } else if (idx < 60928) {
        int i = idx - 56320;
        int t = i >> 9, co = (i >> 5) & 15, ci = i & 31;
        int lci = ((ci & 1) << 4) | (ci >> 1);                 // l2 (dec2 U=2)
        wt[idx] = (co < 3) ? f2bf(dw3[lci * 27 + co * 9 + (8 - t)]) : (ushort_t)0;
    } else if (idx < 61440) {
        int k = idx - 60928;
        float s = 0.f;
        #pragma unroll
        for (int d = 0; d < 16; ++d) { float v = cb[k * 16 + d]; s += v * v; }
        cn[k] = s;
    }
}

// ---------------- zero the pad borders of d1p (one block per image) ---------
__global__ __launch_bounds__(256) void pad_k(ushort_t* __restrict__ d1p) {
    const int img = blockIdx.x, tid = threadIdx.x;
    const uint4 z = (uint4){0, 0, 0, 0};
    uint4* b1 = (uint4*)(d1p + (size_t)img * 1065024);   // 129*129*64 elems
    for (int i = tid; i < 1032; i += 256) b1[132096 + i] = z;   // row 128
    for (int i = tid; i < 1024; i += 256) {                     // col 128
        int r = i >> 3, u = i & 7;
        b1[(r * 129 + 128) * 8 + u] = z;
    }
}

// ---------------- conv1 MFMA: x NCHW fp32 -> a1 [B,128,128,32] (interleaved)
__global__ __launch_bounds__(256, 4) void conv1_k(const float* __restrict__ x,
        const ushort_t* __restrict__ wt, const float* __restrict__ bias,
        ushort_t* __restrict__ a1) {
    const int by = blockIdx.y, b = by >> 7, oh = by & 127;
    const int tid = threadIdx.x;
    __shared__ __align__(16) ushort_t sX[9 * 264];   // [ci*3+kh][iw+1 (258 used)]
    __shared__ int sOff[32];
    for (int i = tid; i < 9 * 264 / 2; i += 256) ((unsigned*)sX)[i] = 0u;
    if (tid < 32) {
        int k = tid, off = 0;
        if (k < 27) { int ci = k / 9, r9 = k % 9, kh = r9 / 3, kw = r9 % 3;
                      off = (ci * 3 + kh) * 264 + kw; }
        sOff[tid] = off;
    }
    __syncthreads();
    #pragma unroll
    for (int it = 0; it < 9; ++it) {
        int slot = it * 256 + tid;                  // 2304 = 3ci * 3kh * 256iw
        int ci = slot / 768, r = slot % 768, kh = r >> 8, iw = r & 255;
        int ih = 2 * oh + kh - 1;
        float v = ((unsigned)ih < 256u) ? x[(long)(b * 3 + ci) * 65536 + ih * 256 + iw] : 0.f;
        sX[(ci * 3 + kh) * 264 + iw + 1] = f2bf(v);
    }
    __syncthreads();
    const int lane = tid & 63, wave = tid >> 6, q = lane >> 4, n16 = lane & 15;
    bf16x8 Bw[2];
    #pragma unroll
    for (int u = 0; u < 2; ++u)
        Bw[u] = *(const bf16x8*)(wt + (u * 16 + n16) * 32 + q * 8);
    f32x4 acc[2][2];
    #pragma unroll
    for (int u = 0; u < 2; ++u) {
        float bz = bias[u * 16 + n16];
        acc[0][u] = (f32x4){bz, bz, bz, bz};
        acc[1][u] = (f32x4){bz, bz, bz, bz};
    }
    #pragma unroll
    for (int mf = 0; mf < 2; ++mf) {
        const int m2 = 2 * (wave * 32 + mf * 16 + n16);
        ushort_t av[8];
        #pragma unroll
        for (int j = 0; j < 8; ++j) {
            int k = q * 8 + j;
            av[j] = (k < 27) ? sX[sOff[k] + m2] : (ushort_t)0;
        }
        bf16x8 A = *(bf16x8*)av;
        #pragma unroll
        for (int u = 0; u < 2; ++u)
            acc[mf][u] = __builtin_amdgcn_mfma_f32_16x16x32_bf16(A, Bw[u], acc[mf][u], 0, 0, 0);
    }
    #pragma unroll
    for (int mf = 0; mf < 2; ++mf)
        #pragma unroll
        for (int r = 0; r < 4; ++r) {
            int ow = wave * 32 + mf * 16 + q * 4 + r;
            *(unsigned*)(a1 + ((long)(b * 128 + oh) * 128 + ow) * 32 + n16 * 2) =
                pack2r(acc[mf][0][r], acc[mf][1][r]);
        }
}

// ---------------- conv2 MFMA: a1 -> a2 [B,64,64,64] (interleaved) -----------
__global__ __launch_bounds__(256, 4) void conv2_k(const ushort_t* __restrict__ a1,
        const ushort_t* __restrict__ wt, const float* __restrict__ bias,
        ushort_t* __restrict__ a2) {
    const int by = blockIdx.y, b = by >> 6, oh = by & 63;
    const int tid = threadIdx.x;
    // parity-split: [kh3][p2][c66][ci32 pad40]
    __shared__ __align__(16) ushort_t sA[3 * 2 * 66 * 40];
    uint4* z4 = (uint4*)sA;
    #pragma unroll
    for (int it = 0; it < 8; ++it) {
        int slot = it * 256 + tid;
        if (slot < 1980) z4[slot] = (uint4){0, 0, 0, 0};
    }
    __syncthreads();
    #pragma unroll
    for (int it = 0; it < 6; ++it) {
        int slot = it * 256 + tid;                    // 1536 = 3kh*128iw*4
        if (slot < 1536) {
            int kh = slot >> 9, rem = slot & 511, iw = rem >> 2, ci8 = (rem & 3) << 3;
            int ih = 2 * oh + kh - 1;
            if ((unsigned)ih < 128u) {
                uint4 v = *(const uint4*)(a1 + ((long)(b * 128 + ih) * 128 + iw) * 32 + ci8);
                int idx = iw + 2, p = idx & 1, c = idx >> 1;
                *(uint4*)&sA[((kh * 2 + p) * 66 + c) * 40 + ci8] = v;
            }
        }
    }
    __syncthreads();
    const int lane = tid & 63, wave = tid >> 6, q = lane >> 4, n16 = lane & 15;
    f32x4 acc[4];
    #pragma unroll
    for (int u = 0; u < 4; ++u) {
        float bz = bias[u * 16 + n16];
        acc[u] = (f32x4){bz, bz, bz, bz};
    }
    const int ow = wave * 16 + n16;   // A row (m)
    #pragma unroll
    for (int t = 0; t < 9; ++t) {
        const int kh = t / 3, kw = t % 3;
        const int p = (kw == 1) ? 0 : 1;
        const int c = (kw == 0) ? ow : ow + 1;
        bf16x8 A = *(bf16x8*)&sA[((kh * 2 + p) * 66 + c) * 40 + q * 8];
        #pragma unroll
        for (int u = 0; u < 4; ++u) {
            bf16x8 B = *(const bf16x8*)(wt + 1024 + t * 2048 + (u * 16 + n16) * 32 + q * 8);
            acc[u] = __builtin_amdgcn_mfma_f32_16x16x32_bf16(A, B, acc[u], 0, 0, 0);
        }
    }
    #pragma unroll
    for (int r = 0; r < 4; ++r) {
        int owo = wave * 16 + q * 4 + r;
        uint2 pk;
        pk.x = pack2r(acc[0][r], acc[1][r]);
        pk.y = pack2r(acc[2][r], acc[3][r]);
        *(uint2*)(a2 + ((long)(b * 64 + oh) * 64 + owo) * 64 + n16 * 4) = pk;
    }
}

// ---------------- conv3 (1x1) + VQ + loss, 2 px/thread ----------------------
__global__ __launch_bounds__(256) void conv3_vq_k(const ushort_t* __restrict__ a2,
        const float* __restrict__ w3, const float* __restrict__ b3,
        const float* __restrict__ cb, const float* __restrict__ cn,
        ushort_t* __restrict__ e, float* __restrict__ acc) {
    const int base = blockIdx.x * 512 + threadIdx.x;   // px0 = base, px1 = base+256
    float z[2][16];
    #pragma unroll
    for (int p = 0; p < 2; ++p)
        #pragma unroll
        for (int d = 0; d < 16; ++d) z[p][d] = b3[d];
    #pragma unroll
    for (int p = 0; p < 2; ++p) {
        const ushort_t* arow = a2 + (long)(base + p * 256) * 64;
        #pragma unroll
        for (int c8 = 0; c8 < 8; ++c8) {
            uint4 raw = *(const uint4*)(arow + c8 * 8);
            ushort_t us[8];
            *(uint4*)us = raw;
            #pragma unroll
            for (int j = 0; j < 8; ++j) {
                int m = c8 * 8 + j;
                int lci = ((m & 3) << 4) | (m >> 2);          // l4
                float a = bf2f(us[j]);
                #pragma unroll
                for (int d = 0; d < 16; ++d)
                    z[p][d] = fmaf(a, w3[d * 64 + lci], z[p][d]);
            }
        }
    }
    const float4* cb4 = (const float4*)cb;
    float best0 = 1e30f, best1 = 1e30f; int bi0 = 0, bi1 = 0;
    for (int k = 0; k < 512; ++k) {
        float4 c0 = cb4[k * 4 + 0], c1 = cb4[k * 4 + 1];
        float4 c2 = cb4[k * 4 + 2], c3 = cb4[k * 4 + 3];
        float nk = cn[k];
        float d0 = z[0][0]*c0.x + z[0][1]*c0.y + z[0][2]*c0.z + z[0][3]*c0.w
                 + z[0][4]*c1.x + z[0][5]*c1.y + z[0][6]*c1.z + z[0][7]*c1.w
                 + z[0][8]*c2.x + z[0][9]*c2.y + z[0][10]*c2.z + z[0][11]*c2.w
                 + z[0][12]*c3.x + z[0][13]*c3.y + z[0][14]*c3.z + z[0][15]*c3.w;
        float d1 = z[1][0]*c0.x + z[1][1]*c0.y + z[1][2]*c0.z + z[1][3]*c0.w
                 + z[1][4]*c1.x + z[1][5]*c1.y + z[1][6]*c1.z + z[1][7]*c1.w
                 + z[1][8]*c2.x + z[1][9]*c2.y + z[1][10]*c2.z + z[1][11]*c2.w
                 + z[1][12]*c3.x + z[1][13]*c3.y + z[1][14]*c3.z + z[1][15]*c3.w;
        float dist0 = nk - 2.f * d0, dist1 = nk - 2.f * d1;
        if (dist0 < best0) { best0 = dist0; bi0 = k; }
        if (dist1 < best1) { best1 = dist1; bi1 = k; }
    }
    float lsum = 0.f;
    #pragma unroll
    for (int d = 0; d < 16; ++d) {
        float q0 = cb[bi0 * 16 + d], q1 = cb[bi1 * 16 + d];
        float f0 = q0 - z[0][d], f1 = q1 - z[1][d];
        lsum += f0 * f0 + f1 * f1;
        e[(long)base * 16 + d] = f2bf(q0);
        e[(long)(base + 256) * 16 + d] = f2bf(q1);
    }
    #pragma unroll
    for (int off = 32; off > 0; off >>= 1) lsum += __shfl_down(lsum, off, 64);
    if ((threadIdx.x & 63) == 0) atomicAdd(&acc[0], lsum);
}

// ---------------- dec1 MFMA: e -> d1p [B,129,129,64] (interleaved) ----------
__global__ __launch_bounds__(256, 4) void dec1_k(const ushort_t* __restrict__ e,
        const ushort_t* __restrict__ wt, const float* __restrict__ bias,
        ushort_t* __restrict__ d1p) {
    const int by = blockIdx.y, b = by >> 6, i = by & 63;
    const int tid = threadIdx.x;
    __shared__ __align__(16) ushort_t sE[2 * 66 * 24];  // [dh2][j66][ci16 pad24]
    uint4* z4 = (uint4*)sE;
    #pragma unroll
    for (int it = 0; it < 2; ++it) {
        int slot = it * 256 + tid;
        if (slot < 396) z4[slot] = (uint4){0, 0, 0, 0};
    }
    __syncthreads();
    {
        int dh = tid >> 7, rem = tid & 127, j = rem >> 1, ci8 = (rem & 1) * 8;
        if (i + dh < 64) {
            uint4 v = *(const uint4*)(e + ((long)((b * 64 + i + dh) * 64 + j)) * 16 + ci8);
            *(uint4*)&sE[(dh * 66 + j) * 24 + ci8] = v;
        }
    }
    __syncthreads();
    const int lane = tid & 63, wave = tid >> 6, q = lane >> 4, n16 = lane & 15;
    f32x4 acc[4][4];   // [class ph*2+pw][ntile]
    #pragma unroll
    for (int u = 0; u < 4; ++u) {
        float bz = bias[u * 16 + n16];
        #pragma unroll
        for (int c = 0; c < 4; ++c) acc[c][u] = (f32x4){bz, bz, bz, bz};
    }
    const int jl = wave * 16 + n16;
    #pragma unroll
    for (int t = 0; t < 9; ++t) {
        const int kh = t / 3, kw = t % 3;
        const int dh = (kh == 0) ? 1 : 0, dw = (kw == 0) ? 1 : 0;
        const int cls = ((kh != 1) ? 2 : 0) | ((kw != 1) ? 1 : 0);
        bf16x8 A = *(bf16x8*)&sE[(dh * 66 + jl + dw) * 24 + (q & 1) * 8];
        #pragma unroll
        for (int u = 0; u < 4; ++u) {
            bf16x8 B = *(const bf16x8*)(wt + 19456 + t * 2048 + (u * 16 + n16) * 32 + q * 8);
            acc[cls][u] = __builtin_amdgcn_mfma_f32_16x16x32_bf16(A, B, acc[cls][u], 0, 0, 0);
        }
    }
    #pragma unroll
    for (int ph = 0; ph < 2; ++ph)
        #pragma unroll
        for (int pw = 0; pw < 2; ++pw)
            #pragma unroll
            for (int r = 0; r < 4; ++r) {
                int oh = 2 * i + ph;
                int ow = 2 * (wave * 16 + q * 4 + r) + pw;
                uint2 pk;
                pk.x = pack2r(acc[ph * 2 + pw][0][r], acc[ph * 2 + pw][1][r]);
                pk.y = pack2r(acc[ph * 2 + pw][2][r], acc[ph * 2 + pw][3][r]);
                *(uint2*)(d1p + (size_t)b * 1065024 + ((long)oh * 129 + ow) * 64 + n16 * 4) = pk;
            }
}

// ---------------- dec23: fused convT(64->32,s2) + conv(32->3) + MSE ---------
// Block: output rows 4*i4..4*i4+3, cols j0..j0+63 (j0 = bx*64).
// Stage 1: d2 rows 4i4-1..4i4+4, cols j0-1..j0+64 (32ch) -> LDS sT (6x68x32).
//   wave w computes d1-row a = 2*i4 + w - 1; s-loop over 3 col-tiles.
// Stage 2: wave -> output row 4i4+wave, 4 M-tiles, flipped-W conv + MSE.
__global__ __launch_bounds__(256, 6) void dec23_k(const ushort_t* __restrict__ d1p,
        const ushort_t* __restrict__ wt, const float* __restrict__ db2,
        const float* __restrict__ db3, const float* __restrict__ x,
        float* __restrict__ acc) {
    const int bx = blockIdx.x, by = blockIdx.y;
    const int b = by >> 6, i4 = by & 63;
    const int j0 = bx << 6;
    const int jd = bx << 5;
    const int tid = threadIdx.x;
    const int lane = tid & 63, wave = tid >> 6, q = lane >> 4, n16 = lane & 15;

    __shared__ __align__(16) ushort_t sT[6 * 68 * 32];   // [R'6][c'68][ch32] 26112 B
    uint4* z4 = (uint4*)sT;
    #pragma unroll
    for (int it = 0; it < 7; ++it) {
        int s = it * 256 + tid;
        if (s < 1632) z4[s] = (uint4){0, 0, 0, 0};
    }
    __syncthreads();

    // ---- stage 1: dec2 rows pair (a) per wave, 3 col-tiles ----
    const int a = 2 * i4 + wave - 1;
    const bool skip0 = (wave == 0);   // d2 row 2a   not in tile
    const bool skip1 = (wave == 3);   // d2 row 2a+1 not in tile
    const ushort_t* dbase = d1p + (size_t)b * 1065024;
    for (int s = 0; s < 3; ++s) {
        const int bcol0 = jd - 1 + s * 16;
        bf16x8 A[2][2][2];   // [kc][dh][dw]
        #pragma unroll
        for (int dh = 0; dh < 2; ++dh) {
            int row = a + dh;
            bool rok = (unsigned)row <= 128u;
            int rowc = rok ? row : 0;
            #pragma unroll
            for (int dw = 0; dw < 2; ++dw) {
                int col = bcol0 + n16 + dw;
                bool cok = (unsigned)col <= 128u;
                int colc = cok ? col : 0;
                const ushort_t* p = dbase + ((long)rowc * 129 + colc) * 64;
                #pragma unroll
                for (int kc = 0; kc < 2; ++kc) {
                    bf16x8 v = *(const bf16x8*)(p + kc * 32 + q * 8);
                    if (!(rok && cok)) v = (bf16x8){0, 0, 0, 0, 0, 0, 0, 0};
                    A[kc][dh][dw] = v;
                }
            }
        }
        f32x4 acc2[4][2];
        #pragma unroll
        for (int u = 0; u < 2; ++u) {
            float bz = db2[u * 16 + n16];
            #pragma unroll
            for (int c = 0; c < 4; ++c) acc2[c][u] = (f32x4){bz, bz, bz, bz};
        }
#define MF23(cls, kh, kw, dh, dw)                                                   \
        _Pragma("unroll")                                                           \
        for (int kc = 0; kc < 2; ++kc)                                              \
            _Pragma("unroll")                                                       \
            for (int u = 0; u < 2; ++u)                                             \
                acc2[cls][u] = __builtin_amdgcn_mfma_f32_16x16x32_bf16(             \
                    A[kc][dh][dw],                                                  \
                    *(const bf16x8*)(wt + 37888 + ((kh) * 3 + (kw)) * 2048 +        \
                                     kc * 1024 + (u * 16 + n16) * 32 + q * 8),      \
                    acc2[cls][u], 0, 0, 0);
        if (!skip0) {
            MF23(0, 1, 1, 0, 0)
            MF23(1, 1, 0, 0, 1)  MF23(1, 1, 2, 0, 0)
        }
        if (!skip1) {
            MF23(2, 0, 1, 1, 0)  MF23(2, 2, 1, 0, 0)
            MF23(3, 0, 0, 1, 1)  MF23(3, 0, 2, 1, 0)  MF23(3, 2, 0, 0, 1)  MF23(3, 2, 2, 0, 0)
        }
#undef MF23
        #pragma unroll
        for (int cls = 0; cls < 4; ++cls) {
            int ph = cls >> 1, pw = cls & 1;
            if ((ph == 0 && skip0) || (ph == 1 && skip1)) continue;
            int R = 2 * a + ph;
            if ((unsigned)R >= 256u) continue;
            int Rp = R - 4 * i4 + 1;                     // in [0,5]
            #pragma unroll
            for (int r = 0; r < 4; ++r) {
                int cg = 2 * (bcol0 + q * 4 + r) + pw;   // global d2 col
                int cp = cg - j0 + 1;                    // tile col
                if ((unsigned)cg < 256u && (unsigned)cp < 66u) {
                    *(unsigned*)&sT[Rp * 2176 + cp * 32 + n16 * 2] =
                        pack2r(acc2[cls][0][r], acc2[cls][1][r]);
                }
            }
        }
    }
    __syncthreads();

    // ---- stage 2: dec3 conv + MSE (wave -> row oh, cols j0..j0+63) ----
    bf16x8 Bw[9];
    #pragma unroll
    for (int t = 0; t < 9; ++t)
        Bw[t] = *(const bf16x8*)(wt + 56320 + t * 512 + n16 * 32 + q * 8);
    float bz3 = (n16 < 3) ? db3[n16] : 0.f;
    f32x4 a4[4];
    #pragma unroll
    for (int mf = 0; mf < 4; ++mf) a4[mf] = (f32x4){bz3, bz3, bz3, bz3};
    const int oh = 4 * i4 + wave;
    #pragma unroll
    for (int kh = 0; kh < 3; ++kh) {
        const ushort_t* srow = &sT[(wave + kh) * 2176];
        #pragma unroll
        for (int mf = 0; mf < 4; ++mf) {
            #pragma unroll
            for (int kw = 0; kw < 3; ++kw) {
                bf16x8 A = *(const bf16x8*)(srow + (mf * 16 + n16 + kw) * 32 + q * 8);
                a4[mf] = __builtin_amdgcn_mfma_f32_16x16x32_bf16(A, Bw[kh * 3 + kw], a4[mf], 0, 0, 0);
            }
        }
    }
    float lsum = 0.f;
    if (n16 < 3) {
        const float* xrow = x + ((long)(b * 3 + n16) * 256 + oh) * 256 + j0;
        #pragma unroll
        for (int mf = 0; mf < 4; ++mf)
            #pragma unroll
            for (int r = 0; r < 4; ++r) {
                int ow = mf * 16 + q * 4 + r;
                float df = a4[mf][r] - xrow[ow];
                lsum += df * df;
            }
    }
    #pragma unroll
    for (int off = 32; off > 0; off >>= 1) lsum += __shfl_down(lsum, off, 64);
    if (lane == 0) atomicAdd(&acc[1], lsum);
}

__global__ void finalize_k(const float* __restrict__ acc, float* __restrict__ out) {
    if (threadIdx.x == 0) {
        float eq  = 1.25f * acc[0] / 4194304.f;     // 262144 px * 16 d
        float mse = acc[1] / 12582912.f;            // 64 * 3 * 256 * 256
        out[0] = eq;
        out[1] = mse;
        out[2] = mse;
    }
}

extern "C" void kernel_launch(void* const* d_in, const int* in_sizes, int n_in,
                              void* d_out, int out_size, void* d_ws, size_t ws_size,
                              hipStream_t stream) {
    (void)in_sizes; (void)n_in; (void)out_size;
    const float* x   = (const float*)d_in[0];
    const float* ew1 = (const float*)d_in[1];
    const float* eb1 = (const float*)d_in[2];
    const float* ew2 = (const float*)d_in[3];
    const float* eb2 = (const float*)d_in[4];
    const float* ew3 = (const float*)d_in[5];
    const float* eb3 = (const float*)d_in[6];
    const float* cb  = (const float*)d_in[7];
    const float* dw1 = (const float*)d_in[8];
    const float* db1 = (const float*)d_in[9];
    const float* dw2 = (const float*)d_in[10];
    const float* db2 = (const float*)d_in[11];
    const float* dw3 = (const float*)d_in[12];
    const float* db3 = (const float*)d_in[13];
    float* out = (float*)d_out;

    // per-image bytes: e 131072 + max(enc a1+a2 = 1572864, dec d1p 2130048)
    // need(C) = 256(acc) + 131072(wbuf) + C*2261120   (C=64 -> 144.8 MB)
    int C = 64;
    while (C > 1 && (size_t)131328 + (size_t)C * 2261120UL > ws_size) C >>= 1;

    char* base = (char*)d_ws;
    float*    acc = (float*)base;
    ushort_t* wt  = (ushort_t*)(base + 256);
    float*    cn  = (float*)(base + 256 + 121856);
    ushort_t* e   = (ushort_t*)(base + 131328);
    char*     rgn = base + 131328 + (size_t)C * 131072UL;
    ushort_t* a1  = (ushort_t*)rgn;
    ushort_t* a2  = (ushort_t*)(rgn + (size_t)C * 1048576UL);
    ushort_t* d1p = (ushort_t*)rgn;                          // reuse (a1/a2 dead)

    zero_k<<<1, 64, 0, stream>>>(acc);
    prep_k<<<240, 256, 0, stream>>>(ew1, ew2, dw1, dw2, dw3, cb, wt, cn);

    for (int b0 = 0; b0 < 64; b0 += C) {
        const float* xc = x + (size_t)b0 * 196608UL;
        conv1_k   <<<dim3(1, C * 128), 256, 0, stream>>>(xc,  wt, eb1, a1);
        conv2_k   <<<dim3(1, C * 64),  256, 0, stream>>>(a1,  wt, eb2, a2);
        conv3_vq_k<<<dim3(C * 8),      256, 0, stream>>>(a2,  ew3, eb3, cb, cn, e, acc);
        pad_k     <<<dim3(C),          256, 0, stream>>>(d1p);
        dec1_k    <<<dim3(1, C * 64),  256, 0, stream>>>(e,   wt, db1, d1p);
        dec23_k   <<<dim3(4, C * 64),  256, 0, stream>>>(d1p, wt, db2, db3, xc, acc);
    }
    finalize_k<<<1, 64, 0, stream>>>(acc, out);
}

// Round 11
// 1321.762 us; speedup vs baseline: 1.1289x; 1.1289x over previous
//
#include <hip/hip_runtime.h>
#include <hip/hip_bf16.h>

// VQ-VAE forward — NHWC bf16 intermediates, MFMA (16x16x32 bf16) for all convs.
// Outputs: [1.25*vq_mse, recon_mse, recon_mse]
//
// MFMA lane layouts (gfx950, HW-verified per guide):
//   A: m = lane&15, k = (lane>>4)*8 + j     (8 bf16 / lane)
//   B: n = lane&15, k = (lane>>4)*8 + j
//   D: n = lane&15, m = (lane>>4)*4 + reg   (4 f32 / lane)
//
// CHANNEL-INTERLEAVED storage: a producer with U=Cc/16 tiles stores tile u,
// column n16 (logical co = u*16+n16) at memory channel m = n16*U+u; consumers
// permute ci in weight prep: logical l(m) = (m%U)*16 + m/U.
//
// dec2+dec3 FUSED (dec23_k): d2 never touches HBM. Block = 4 output rows x
// 64 cols; stage 1 computes the 6x66-px d2 tile (32ch) into 25.5 KB LDS;
// stage 2 runs the stride-1 conv (flipped dw3) + fused MSE.
// NOTE: launch_bounds min-waves MUST stay at 4 — 6 forced VGPR<=85 and the
// compiler spilled to scratch (+1 GB HBM traffic, 2x slower — R9 post-mortem).
//
// d1p [B][129][129][64]: interior (0,0)..(127,127); pad row/col 128 = 0.

typedef __attribute__((ext_vector_type(8))) short bf16x8;
typedef __attribute__((ext_vector_type(4))) float f32x4;
typedef unsigned short ushort_t;

__device__ __forceinline__ ushort_t f2bf(float v) {
    __hip_bfloat16 h = __float2bfloat16(v);
    return *(ushort_t*)&h;
}
__device__ __forceinline__ float bf2f(ushort_t u) {
    __hip_bfloat16 h = *(__hip_bfloat16*)&u;
    return __bfloat162float(h);
}
__device__ __forceinline__ unsigned pack2r(float a, float b) {   // relu+pack
    return (unsigned)f2bf(fmaxf(a, 0.f)) | ((unsigned)f2bf(fmaxf(b, 0.f)) << 16);
}

// Transformed-weight layout in wbuf (elements of bf16):
//   W1T  @ 0      [co32][k32]            (k=ci*9+kh*3+kw, pad 27->32)
//   W2T  @ 1024   [t9][co64][ci32]       (ci permuted: l2(ci))
//   WD1  @ 19456  [t9][co64][k32]        (k<16 = ci natural, else 0)
//   WD2  @ 37888  [t9][kc2][co32][ci32]  (ci permuted: l4(kc*32+ci))
//   WD3  @ 56320  [t9][co16][ci32]       (taps FLIPPED: src 8-t; ci perm l2; co>=3 -> 0)
//   cn (fp32, 512) @ byte offset 121856

__global__ void zero_k(float* __restrict__ acc) { acc[threadIdx.x] = 0.f; }

__global__ __launch_bounds__(256) void prep_k(
        const float* __restrict__ ew1, const float* __restrict__ ew2,
        const float* __restrict__ dw1, const float* __restrict__ dw2,
        const float* __restrict__ dw3, const float* __restrict__ cb,
        ushort_t* __restrict__ wt, float* __restrict__ cn) {
    int idx = blockIdx.x * 256 + threadIdx.x;
    if (idx < 1024) {
        int co = idx >> 5, k = idx & 31;
        wt[idx] = (k < 27) ? f2bf(ew1[co * 27 + k]) : (ushort_t)0;
    } else if (idx < 19456) {
        int i = idx - 1024;
        int t = i >> 11, co = (i >> 5) & 63, ci = i & 31;
        int lci = ((ci & 1) << 4) | (ci >> 1);                 // l2 (conv1 U=2)
        wt[idx] = f2bf(ew2[co * 288 + lci * 9 + t]);
    } else if (idx < 37888) {
        int i = idx - 19456;
        int t = i >> 11, co = (i >> 5) & 63, k = i & 31;
        wt[idx] = (k < 16) ? f2bf(dw1[k * 576 + co * 9 + t]) : (ushort_t)0;
    } else if (idx < 56320) {
        int i = idx - 37888;
        int t = i >> 11, kc = (i >> 10) & 1, co = (i >> 5) & 31, ci = i & 31;
        int m = kc * 32 + ci;
        int lci = ((m & 3) << 4) | (m >> 2);                   // l4 (dec1 U=4)
        wt[idx] = f2bf(dw2[lci * 288 + co * 9 + t]);
    } else if (idx < 60928) {
        int i = idx - 56320;
        int t = i >> 9, co = (i >> 5) & 15, ci = i & 31;
        int lci = ((ci & 1) << 4) | (ci >> 1);                 // l2 (dec2 U=2)
        wt[idx] = (co < 3) ? f2bf(dw3[lci * 27 + co * 9 + (8 - t)]) : (ushort_t)0;
    } else if (idx < 61440) {
        int k = idx - 60928;
        float s = 0.f;
        #pragma unroll
        for (int d = 0; d < 16; ++d) { float v = cb[k * 16 + d]; s += v * v; }
        cn[k] = s;
    }
}

// ---------------- zero the pad borders of d1p (one block per image) ---------
__global__ __launch_bounds__(256) void pad_k(ushort_t* __restrict__ d1p) {
    const int img = blockIdx.x, tid = threadIdx.x;
    const uint4 z = (uint4){0, 0, 0, 0};
    uint4* b1 = (uint4*)(d1p + (size_t)img * 1065024);   // 129*129*64 elems
    for (int i = tid; i < 1032; i += 256) b1[132096 + i] = z;   // row 128
    for (int i = tid; i < 1024; i += 256) {                     // col 128
        int r = i >> 3, u = i & 7;
        b1[(r * 129 + 128) * 8 + u] = z;
    }
}

// ---------------- conv1 MFMA: x NCHW fp32 -> a1 [B,128,128,32] (interleaved)
__global__ __launch_bounds__(256, 4) void conv1_k(const float* __restrict__ x,
        const ushort_t* __restrict__ wt, const float* __restrict__ bias,
        ushort_t* __restrict__ a1) {
    const int by = blockIdx.y, b = by >> 7, oh = by & 127;
    const int tid = threadIdx.x;
    __shared__ __align__(16) ushort_t sX[9 * 264];   // [ci*3+kh][iw+1 (258 used)]
    __shared__ int sOff[32];
    for (int i = tid; i < 9 * 264 / 2; i += 256) ((unsigned*)sX)[i] = 0u;
    if (tid < 32) {
        int k = tid, off = 0;
        if (k < 27) { int ci = k / 9, r9 = k % 9, kh = r9 / 3, kw = r9 % 3;
                      off = (ci * 3 + kh) * 264 + kw; }
        sOff[tid] = off;
    }
    __syncthreads();
    #pragma unroll
    for (int it = 0; it < 9; ++it) {
        int slot = it * 256 + tid;                  // 2304 = 3ci * 3kh * 256iw
        int ci = slot / 768, r = slot % 768, kh = r >> 8, iw = r & 255;
        int ih = 2 * oh + kh - 1;
        float v = ((unsigned)ih < 256u) ? x[(long)(b * 3 + ci) * 65536 + ih * 256 + iw] : 0.f;
        sX[(ci * 3 + kh) * 264 + iw + 1] = f2bf(v);
    }
    __syncthreads();
    const int lane = tid & 63, wave = tid >> 6, q = lane >> 4, n16 = lane & 15;
    bf16x8 Bw[2];
    #pragma unroll
    for (int u = 0; u < 2; ++u)
        Bw[u] = *(const bf16x8*)(wt + (u * 16 + n16) * 32 + q * 8);
    f32x4 acc[2][2];
    #pragma unroll
    for (int u = 0; u < 2; ++u) {
        float bz = bias[u * 16 + n16];
        acc[0][u] = (f32x4){bz, bz, bz, bz};
        acc[1][u] = (f32x4){bz, bz, bz, bz};
    }
    #pragma unroll
    for (int mf = 0; mf < 2; ++mf) {
        const int m2 = 2 * (wave * 32 + mf * 16 + n16);
        ushort_t av[8];
        #pragma unroll
        for (int j = 0; j < 8; ++j) {
            int k = q * 8 + j;
            av[j] = (k < 27) ? sX[sOff[k] + m2] : (ushort_t)0;
        }
        bf16x8 A = *(bf16x8*)av;
        #pragma unroll
        for (int u = 0; u < 2; ++u)
            acc[mf][u] = __builtin_amdgcn_mfma_f32_16x16x32_bf16(A, Bw[u], acc[mf][u], 0, 0, 0);
    }
    #pragma unroll
    for (int mf = 0; mf < 2; ++mf)
        #pragma unroll
        for (int r = 0; r < 4; ++r) {
            int ow = wave * 32 + mf * 16 + q * 4 + r;
            *(unsigned*)(a1 + ((long)(b * 128 + oh) * 128 + ow) * 32 + n16 * 2) =
                pack2r(acc[mf][0][r], acc[mf][1][r]);
        }
}

// ---------------- conv2 MFMA: a1 -> a2 [B,64,64,64] (interleaved) -----------
__global__ __launch_bounds__(256, 4) void conv2_k(const ushort_t* __restrict__ a1,
        const ushort_t* __restrict__ wt, const float* __restrict__ bias,
        ushort_t* __restrict__ a2) {
    const int by = blockIdx.y, b = by >> 6, oh = by & 63;
    const int tid = threadIdx.x;
    // parity-split: [kh3][p2][c66][ci32 pad40]
    __shared__ __align__(16) ushort_t sA[3 * 2 * 66 * 40];
    uint4* z4 = (uint4*)sA;
    #pragma unroll
    for (int it = 0; it < 8; ++it) {
        int slot = it * 256 + tid;
        if (slot < 1980) z4[slot] = (uint4){0, 0, 0, 0};
    }
    __syncthreads();
    #pragma unroll
    for (int it = 0; it < 6; ++it) {
        int slot = it * 256 + tid;                    // 1536 = 3kh*128iw*4
        if (slot < 1536) {
            int kh = slot >> 9, rem = slot & 511, iw = rem >> 2, ci8 = (rem & 3) << 3;
            int ih = 2 * oh + kh - 1;
            if ((unsigned)ih < 128u) {
                uint4 v = *(const uint4*)(a1 + ((long)(b * 128 + ih) * 128 + iw) * 32 + ci8);
                int idx = iw + 2, p = idx & 1, c = idx >> 1;
                *(uint4*)&sA[((kh * 2 + p) * 66 + c) * 40 + ci8] = v;
            }
        }
    }
    __syncthreads();
    const int lane = tid & 63, wave = tid >> 6, q = lane >> 4, n16 = lane & 15;
    f32x4 acc[4];
    #pragma unroll
    for (int u = 0; u < 4; ++u) {
        float bz = bias[u * 16 + n16];
        acc[u] = (f32x4){bz, bz, bz, bz};
    }
    const int ow = wave * 16 + n16;   // A row (m)
    #pragma unroll
    for (int t = 0; t < 9; ++t) {
        const int kh = t / 3, kw = t % 3;
        const int p = (kw == 1) ? 0 : 1;
        const int c = (kw == 0) ? ow : ow + 1;
        bf16x8 A = *(bf16x8*)&sA[((kh * 2 + p) * 66 + c) * 40 + q * 8];
        #pragma unroll
        for (int u = 0; u < 4; ++u) {
            bf16x8 B = *(const bf16x8*)(wt + 1024 + t * 2048 + (u * 16 + n16) * 32 + q * 8);
            acc[u] = __builtin_amdgcn_mfma_f32_16x16x32_bf16(A, B, acc[u], 0, 0, 0);
        }
    }
    #pragma unroll
    for (int r = 0; r < 4; ++r) {
        int owo = wave * 16 + q * 4 + r;
        uint2 pk;
        pk.x = pack2r(acc[0][r], acc[1][r]);
        pk.y = pack2r(acc[2][r], acc[3][r]);
        *(uint2*)(a2 + ((long)(b * 64 + oh) * 64 + owo) * 64 + n16 * 4) = pk;
    }
}

// ---------------- conv3 (1x1) + VQ + loss, 2 px/thread ----------------------
__global__ __launch_bounds__(256) void conv3_vq_k(const ushort_t* __restrict__ a2,
        const float* __restrict__ w3, const float* __restrict__ b3,
        const float* __restrict__ cb, const float* __restrict__ cn,
        ushort_t* __restrict__ e, float* __restrict__ acc) {
    const int base = blockIdx.x * 512 + threadIdx.x;   // px0 = base, px1 = base+256
    float z[2][16];
    #pragma unroll
    for (int p = 0; p < 2; ++p)
        #pragma unroll
        for (int d = 0; d < 16; ++d) z[p][d] = b3[d];
    #pragma unroll
    for (int p = 0; p < 2; ++p) {
        const ushort_t* arow = a2 + (long)(base + p * 256) * 64;
        #pragma unroll
        for (int c8 = 0; c8 < 8; ++c8) {
            uint4 raw = *(const uint4*)(arow + c8 * 8);
            ushort_t us[8];
            *(uint4*)us = raw;
            #pragma unroll
            for (int j = 0; j < 8; ++j) {
                int m = c8 * 8 + j;
                int lci = ((m & 3) << 4) | (m >> 2);          // l4
                float a = bf2f(us[j]);
                #pragma unroll
                for (int d = 0; d < 16; ++d)
                    z[p][d] = fmaf(a, w3[d * 64 + lci], z[p][d]);
            }
        }
    }
    const float4* cb4 = (const float4*)cb;
    float best0 = 1e30f, best1 = 1e30f; int bi0 = 0, bi1 = 0;
    for (int k = 0; k < 512; ++k) {
        float4 c0 = cb4[k * 4 + 0], c1 = cb4[k * 4 + 1];
        float4 c2 = cb4[k * 4 + 2], c3 = cb4[k * 4 + 3];
        float nk = cn[k];
        float d0 = z[0][0]*c0.x + z[0][1]*c0.y + z[0][2]*c0.z + z[0][3]*c0.w
                 + z[0][4]*c1.x + z[0][5]*c1.y + z[0][6]*c1.z + z[0][7]*c1.w
                 + z[0][8]*c2.x + z[0][9]*c2.y + z[0][10]*c2.z + z[0][11]*c2.w
                 + z[0][12]*c3.x + z[0][13]*c3.y + z[0][14]*c3.z + z[0][15]*c3.w;
        float d1 = z[1][0]*c0.x + z[1][1]*c0.y + z[1][2]*c0.z + z[1][3]*c0.w
                 + z[1][4]*c1.x + z[1][5]*c1.y + z[1][6]*c1.z + z[1][7]*c1.w
                 + z[1][8]*c2.x + z[1][9]*c2.y + z[1][10]*c2.z + z[1][11]*c2.w
                 + z[1][12]*c3.x + z[1][13]*c3.y + z[1][14]*c3.z + z[1][15]*c3.w;
        float dist0 = nk - 2.f * d0, dist1 = nk - 2.f * d1;
        if (dist0 < best0) { best0 = dist0; bi0 = k; }
        if (dist1 < best1) { best1 = dist1; bi1 = k; }
    }
    float lsum = 0.f;
    #pragma unroll
    for (int d = 0; d < 16; ++d) {
        float q0 = cb[bi0 * 16 + d], q1 = cb[bi1 * 16 + d];
        float f0 = q0 - z[0][d], f1 = q1 - z[1][d];
        lsum += f0 * f0 + f1 * f1;
        e[(long)base * 16 + d] = f2bf(q0);
        e[(long)(base + 256) * 16 + d] = f2bf(q1);
    }
    #pragma unroll
    for (int off = 32; off > 0; off >>= 1) lsum += __shfl_down(lsum, off, 64);
    if ((threadIdx.x & 63) == 0) atomicAdd(&acc[0], lsum);
}

// ---------------- dec1 MFMA: e -> d1p [B,129,129,64] (interleaved) ----------
__global__ __launch_bounds__(256, 4) void dec1_k(const ushort_t* __restrict__ e,
        const ushort_t* __restrict__ wt, const float* __restrict__ bias,
        ushort_t* __restrict__ d1p) {
    const int by = blockIdx.y, b = by >> 6, i = by & 63;
    const int tid = threadIdx.x;
    __shared__ __align__(16) ushort_t sE[2 * 66 * 24];  // [dh2][j66][ci16 pad24]
    uint4* z4 = (uint4*)sE;
    #pragma unroll
    for (int it = 0; it < 2; ++it) {
        int slot = it * 256 + tid;
        if (slot < 396) z4[slot] = (uint4){0, 0, 0, 0};
    }
    __syncthreads();
    {
        int dh = tid >> 7, rem = tid & 127, j = rem >> 1, ci8 = (rem & 1) * 8;
        if (i + dh < 64) {
            uint4 v = *(const uint4*)(e + ((long)((b * 64 + i + dh) * 64 + j)) * 16 + ci8);
            *(uint4*)&sE[(dh * 66 + j) * 24 + ci8] = v;
        }
    }
    __syncthreads();
    const int lane = tid & 63, wave = tid >> 6, q = lane >> 4, n16 = lane & 15;
    f32x4 acc[4][4];   // [class ph*2+pw][ntile]
    #pragma unroll
    for (int u = 0; u < 4; ++u) {
        float bz = bias[u * 16 + n16];
        #pragma unroll
        for (int c = 0; c < 4; ++c) acc[c][u] = (f32x4){bz, bz, bz, bz};
    }
    const int jl = wave * 16 + n16;
    #pragma unroll
    for (int t = 0; t < 9; ++t) {
        const int kh = t / 3, kw = t % 3;
        const int dh = (kh == 0) ? 1 : 0, dw = (kw == 0) ? 1 : 0;
        const int cls = ((kh != 1) ? 2 : 0) | ((kw != 1) ? 1 : 0);
        bf16x8 A = *(bf16x8*)&sE[(dh * 66 + jl + dw) * 24 + (q & 1) * 8];
        #pragma unroll
        for (int u = 0; u < 4; ++u) {
            bf16x8 B = *(const bf16x8*)(wt + 19456 + t * 2048 + (u * 16 + n16) * 32 + q * 8);
            acc[cls][u] = __builtin_amdgcn_mfma_f32_16x16x32_bf16(A, B, acc[cls][u], 0, 0, 0);
        }
    }
    #pragma unroll
    for (int ph = 0; ph < 2; ++ph)
        #pragma unroll
        for (int pw = 0; pw < 2; ++pw)
            #pragma unroll
            for (int r = 0; r < 4; ++r) {
                int oh = 2 * i + ph;
                int ow = 2 * (wave * 16 + q * 4 + r) + pw;
                uint2 pk;
                pk.x = pack2r(acc[ph * 2 + pw][0][r], acc[ph * 2 + pw][1][r]);
                pk.y = pack2r(acc[ph * 2 + pw][2][r], acc[ph * 2 + pw][3][r]);
                *(uint2*)(d1p + (size_t)b * 1065024 + ((long)oh * 129 + ow) * 64 + n16 * 4) = pk;
            }
}

// ---------------- dec23: fused convT(64->32,s2) + conv(32->3) + MSE ---------
// Block: output rows 4*i4..4*i4+3, cols j0..j0+63 (j0 = bx*64).
// Stage 1: d2 rows 4i4-1..4i4+4, cols j0-1..j0+64 (32ch) -> LDS sT (6x68x32).
//   wave w computes d1-row a = 2*i4 + w - 1; s-loop over 3 col-tiles.
// Stage 2: wave -> output row 4i4+wave, 4 M-tiles, flipped-W conv + MSE.
__global__ __launch_bounds__(256, 4) void dec23_k(const ushort_t* __restrict__ d1p,
        const ushort_t* __restrict__ wt, const float* __restrict__ db2,
        const float* __restrict__ db3, const float* __restrict__ x,
        float* __restrict__ acc) {
    const int bx = blockIdx.x, by = blockIdx.y;
    const int b = by >> 6, i4 = by & 63;
    const int j0 = bx << 6;
    const int jd = bx << 5;
    const int tid = threadIdx.x;
    const int lane = tid & 63, wave = tid >> 6, q = lane >> 4, n16 = lane & 15;

    __shared__ __align__(16) ushort_t sT[6 * 68 * 32];   // [R'6][c'68][ch32] 26112 B
    uint4* z4 = (uint4*)sT;
    #pragma unroll
    for (int it = 0; it < 7; ++it) {
        int s = it * 256 + tid;
        if (s < 1632) z4[s] = (uint4){0, 0, 0, 0};
    }
    __syncthreads();

    // ---- stage 1: dec2 rows pair (a) per wave, 3 col-tiles ----
    const int a = 2 * i4 + wave - 1;
    const bool skip0 = (wave == 0);   // d2 row 2a   not in tile
    const bool skip1 = (wave == 3);   // d2 row 2a+1 not in tile
    const ushort_t* dbase = d1p + (size_t)b * 1065024;
    for (int s = 0; s < 3; ++s) {
        const int bcol0 = jd - 1 + s * 16;
        bf16x8 A[2][2][2];   // [kc][dh][dw]
        #pragma unroll
        for (int dh = 0; dh < 2; ++dh) {
            int row = a + dh;
            bool rok = (unsigned)row <= 128u;
            int rowc = rok ? row : 0;
            #pragma unroll
            for (int dw = 0; dw < 2; ++dw) {
                int col = bcol0 + n16 + dw;
                bool cok = (unsigned)col <= 128u;
                int colc = cok ? col : 0;
                const ushort_t* p = dbase + ((long)rowc * 129 + colc) * 64;
                #pragma unroll
                for (int kc = 0; kc < 2; ++kc) {
                    bf16x8 v = *(const bf16x8*)(p + kc * 32 + q * 8);
                    if (!(rok && cok)) v = (bf16x8){0, 0, 0, 0, 0, 0, 0, 0};
                    A[kc][dh][dw] = v;
                }
            }
        }
        f32x4 acc2[4][2];
        #pragma unroll
        for (int u = 0; u < 2; ++u) {
            float bz = db2[u * 16 + n16];
            #pragma unroll
            for (int c = 0; c < 4; ++c) acc2[c][u] = (f32x4){bz, bz, bz, bz};
        }
#define MF23(cls, kh, kw, dh, dw)                                                   \
        _Pragma("unroll")                                                           \
        for (int kc = 0; kc < 2; ++kc)                                              \
            _Pragma("unroll")                                                       \
            for (int u = 0; u < 2; ++u)                                             \
                acc2[cls][u] = __builtin_amdgcn_mfma_f32_16x16x32_bf16(             \
                    A[kc][dh][dw],                                                  \
                    *(const bf16x8*)(wt + 37888 + ((kh) * 3 + (kw)) * 2048 +        \
                                     kc * 1024 + (u * 16 + n16) * 32 + q * 8),      \
                    acc2[cls][u], 0, 0, 0);
        if (!skip0) {
            MF23(0, 1, 1, 0, 0)
            MF23(1, 1, 0, 0, 1)  MF23(1, 1, 2, 0, 0)
        }
        if (!skip1) {
            MF23(2, 0, 1, 1, 0)  MF23(2, 2, 1, 0, 0)
            MF23(3, 0, 0, 1, 1)  MF23(3, 0, 2, 1, 0)  MF23(3, 2, 0, 0, 1)  MF23(3, 2, 2, 0, 0)
        }
#undef MF23
        #pragma unroll
        for (int cls = 0; cls < 4; ++cls) {
            int ph = cls >> 1, pw = cls & 1;
            if ((ph == 0 && skip0) || (ph == 1 && skip1)) continue;
            int R = 2 * a + ph;
            if ((unsigned)R >= 256u) continue;
            int Rp = R - 4 * i4 + 1;                     // in [0,5]
            #pragma unroll
            for (int r = 0; r < 4; ++r) {
                int cg = 2 * (bcol0 + q * 4 + r) + pw;   // global d2 col
                int cp = cg - j0 + 1;                    // tile col
                if ((unsigned)cg < 256u && (unsigned)cp < 66u) {
                    *(unsigned*)&sT[Rp * 2176 + cp * 32 + n16 * 2] =
                        pack2r(acc2[cls][0][r], acc2[cls][1][r]);
                }
            }
        }
    }
    __syncthreads();

    // ---- stage 2: dec3 conv + MSE (wave -> row oh, cols j0..j0+63) ----
    bf16x8 Bw[9];
    #pragma unroll
    for (int t = 0; t < 9; ++t)
        Bw[t] = *(const bf16x8*)(wt + 56320 + t * 512 + n16 * 32 + q * 8);
    float bz3 = (n16 < 3) ? db3[n16] : 0.f;
    f32x4 a4[4];
    #pragma unroll
    for (int mf = 0; mf < 4; ++mf) a4[mf] = (f32x4){bz3, bz3, bz3, bz3};
    const int oh = 4 * i4 + wave;
    #pragma unroll
    for (int kh = 0; kh < 3; ++kh) {
        const ushort_t* srow = &sT[(wave + kh) * 2176];
        #pragma unroll
        for (int mf = 0; mf < 4; ++mf) {
            #pragma unroll
            for (int kw = 0; kw < 3; ++kw) {
                bf16x8 A = *(const bf16x8*)(srow + (mf * 16 + n16 + kw) * 32 + q * 8);
                a4[mf] = __builtin_amdgcn_mfma_f32_16x16x32_bf16(A, Bw[kh * 3 + kw], a4[mf], 0, 0, 0);
            }
        }
    }
    float lsum = 0.f;
    if (n16 < 3) {
        const float* xrow = x + ((long)(b * 3 + n16) * 256 + oh) * 256 + j0;
        #pragma unroll
        for (int mf = 0; mf < 4; ++mf)
            #pragma unroll
            for (int r = 0; r < 4; ++r) {
                int ow = mf * 16 + q * 4 + r;
                float df = a4[mf][r] - xrow[ow];
                lsum += df * df;
            }
    }
    #pragma unroll
    for (int off = 32; off > 0; off >>= 1) lsum += __shfl_down(lsum, off, 64);
    if (lane == 0) atomicAdd(&acc[1], lsum);
}

__global__ void finalize_k(const float* __restrict__ acc, float* __restrict__ out) {
    if (threadIdx.x == 0) {
        float eq  = 1.25f * acc[0] / 4194304.f;     // 262144 px * 16 d
        float mse = acc[1] / 12582912.f;            // 64 * 3 * 256 * 256
        out[0] = eq;
        out[1] = mse;
        out[2] = mse;
    }
}

extern "C" void kernel_launch(void* const* d_in, const int* in_sizes, int n_in,
                              void* d_out, int out_size, void* d_ws, size_t ws_size,
                              hipStream_t stream) {
    (void)in_sizes; (void)n_in; (void)out_size;
    const float* x   = (const float*)d_in[0];
    const float* ew1 = (const float*)d_in[1];
    const float* eb1 = (const float*)d_in[2];
    const float* ew2 = (const float*)d_in[3];
    const float* eb2 = (const float*)d_in[4];
    const float* ew3 = (const float*)d_in[5];
    const float* eb3 = (const float*)d_in[6];
    const float* cb  = (const float*)d_in[7];
    const float* dw1 = (const float*)d_in[8];
    const float* db1 = (const float*)d_in[9];
    const float* dw2 = (const float*)d_in[10];
    const float* db2 = (const float*)d_in[11];
    const float* dw3 = (const float*)d_in[12];
    const float* db3 = (const float*)d_in[13];
    float* out = (float*)d_out;

    // per-image bytes: e 131072 + max(enc a1+a2 = 1572864, dec d1p 2130048)
    // need(C) = 256(acc) + 131072(wbuf) + C*2261120   (C=64 -> 144.8 MB)
    int C = 64;
    while (C > 1 && (size_t)131328 + (size_t)C * 2261120UL > ws_size) C >>= 1;

    char* base = (char*)d_ws;
    float*    acc = (float*)base;
    ushort_t* wt  = (ushort_t*)(base + 256);
    float*    cn  = (float*)(base + 256 + 121856);
    ushort_t* e   = (ushort_t*)(base + 131328);
    char*     rgn = base + 131328 + (size_t)C * 131072UL;
    ushort_t* a1  = (ushort_t*)rgn;
    ushort_t* a2  = (ushort_t*)(rgn + (size_t)C * 1048576UL);
    ushort_t* d1p = (ushort_t*)rgn;                          // reuse (a1/a2 dead)

    zero_k<<<1, 64, 0, stream>>>(acc);
    prep_k<<<240, 256, 0, stream>>>(ew1, ew2, dw1, dw2, dw3, cb, wt, cn);

    for (int b0 = 0; b0 < 64; b0 += C) {
        const float* xc = x + (size_t)b0 * 196608UL;
        conv1_k   <<<dim3(1, C * 128), 256, 0, stream>>>(xc,  wt, eb1, a1);
        conv2_k   <<<dim3(1, C * 64),  256, 0, stream>>>(a1,  wt, eb2, a2);
        conv3_vq_k<<<dim3(C * 8),      256, 0, stream>>>(a2,  ew3, eb3, cb, cn, e, acc);
        pad_k     <<<dim3(C),          256, 0, stream>>>(d1p);
        dec1_k    <<<dim3(1, C * 64),  256, 0, stream>>>(e,   wt, db1, d1p);
        dec23_k   <<<dim3(4, C * 64),  256, 0, stream>>>(d1p, wt, db2, db3, xc, acc);
    }
    finalize_k<<<1, 64, 0, stream>>>(acc, out);
}

// Round 12
// 965.964 us; speedup vs baseline: 1.5447x; 1.3683x over previous
//
#include <hip/hip_runtime.h>
#include <hip/hip_bf16.h>

// VQ-VAE forward — NHWC bf16 intermediates, MFMA (16x16x32 bf16) for all convs.
// Outputs: [1.25*vq_mse, recon_mse, recon_mse]
//
// MFMA lane layouts (gfx950, HW-verified per guide):
//   A: m = lane&15, k = (lane>>4)*8 + j     (8 bf16 / lane)
//   B: n = lane&15, k = (lane>>4)*8 + j
//   D: n = lane&15, m = (lane>>4)*4 + reg   (4 f32 / lane)
//
// CHANNEL-INTERLEAVED storage: a producer with U=Cc/16 tiles stores tile u,
// column n16 (logical co = u*16+n16) at memory channel m = n16*U+u; consumers
// permute ci in weight prep: logical l(m) = (m%U)*16 + m/U.
//
// dec2+dec3 FUSED (dec23_k): d2 never touches HBM. Block = 4 output rows x
// 128 cols (6x132x32 LDS tile). Stage-1 accumulators are SPLIT BY kc
// (acc2[cls][u][kc]) so each MFMA chain is half as deep and 16 chains run
// independently — the B-fragment L2 loads pipeline instead of serializing
// (R11 post-mortem: in-chain B loads cost ~300 cy/MFMA).
// NOTE: launch_bounds min-waves must stay <=4: 6 forced VGPR<=85 -> scratch
// spill, +1 GB HBM, 2x slower (R9/R10 post-mortem).
//
// d1p [B][129][129][64]: interior (0,0)..(127,127); pad row/col 128 = 0.

typedef __attribute__((ext_vector_type(8))) short bf16x8;
typedef __attribute__((ext_vector_type(4))) float f32x4;
typedef unsigned short ushort_t;

__device__ __forceinline__ ushort_t f2bf(float v) {
    __hip_bfloat16 h = __float2bfloat16(v);
    return *(ushort_t*)&h;
}
__device__ __forceinline__ float bf2f(ushort_t u) {
    __hip_bfloat16 h = *(__hip_bfloat16*)&u;
    return __bfloat162float(h);
}
__device__ __forceinline__ unsigned pack2r(float a, float b) {   // relu+pack
    return (unsigned)f2bf(fmaxf(a, 0.f)) | ((unsigned)f2bf(fmaxf(b, 0.f)) << 16);
}

// Transformed-weight layout in wbuf (elements of bf16):
//   W1T  @ 0      [co32][k32]            (k=ci*9+kh*3+kw, pad 27->32)
//   W2T  @ 1024   [t9][co64][ci32]       (ci permuted: l2(ci))
//   WD1  @ 19456  [t9][co64][k32]        (k<16 = ci natural, else 0)
//   WD2  @ 37888  [t9][kc2][co32][ci32]  (ci permuted: l4(kc*32+ci))
//   WD3  @ 56320  [t9][co16][ci32]       (taps FLIPPED: src 8-t; ci perm l2; co>=3 -> 0)
//   cn (fp32, 512) @ byte offset 121856

__global__ void zero_k(float* __restrict__ acc) { acc[threadIdx.x] = 0.f; }

__global__ __launch_bounds__(256) void prep_k(
        const float* __restrict__ ew1, const float* __restrict__ ew2,
        const float* __restrict__ dw1, const float* __restrict__ dw2,
        const float* __restrict__ dw3, const float* __restrict__ cb,
        ushort_t* __restrict__ wt, float* __restrict__ cn) {
    int idx = blockIdx.x * 256 + threadIdx.x;
    if (idx < 1024) {
        int co = idx >> 5, k = idx & 31;
        wt[idx] = (k < 27) ? f2bf(ew1[co * 27 + k]) : (ushort_t)0;
    } else if (idx < 19456) {
        int i = idx - 1024;
        int t = i >> 11, co = (i >> 5) & 63, ci = i & 31;
        int lci = ((ci & 1) << 4) | (ci >> 1);                 // l2 (conv1 U=2)
        wt[idx] = f2bf(ew2[co * 288 + lci * 9 + t]);
    } else if (idx < 37888) {
        int i = idx - 19456;
        int t = i >> 11, co = (i >> 5) & 63, k = i & 31;
        wt[idx] = (k < 16) ? f2bf(dw1[k * 576 + co * 9 + t]) : (ushort_t)0;
    } else if (idx < 56320) {
        int i = idx - 37888;
        int t = i >> 11, kc = (i >> 10) & 1, co = (i >> 5) & 31, ci = i & 31;
        int m = kc * 32 + ci;
        int lci = ((m & 3) << 4) | (m >> 2);                   // l4 (dec1 U=4)
        wt[idx] = f2bf(dw2[lci * 288 + co * 9 + t]);
    } else if (idx < 60928) {
        int i = idx - 56320;
        int t = i >> 9, co = (i >> 5) & 15, ci = i & 31;
        int lci = ((ci & 1) << 4) | (ci >> 1);                 // l2 (dec2 U=2)
        wt[idx] = (co < 3) ? f2bf(dw3[lci * 27 + co * 9 + (8 - t)]) : (ushort_t)0;
    } else if (idx < 61440) {
        int k = idx - 60928;
        float s = 0.f;
        #pragma unroll
        for (int d = 0; d < 16; ++d) { float v = cb[k * 16 + d]; s += v * v; }
        cn[k] = s;
    }
}

// ---------------- zero the pad borders of d1p (one block per image) ---------
__global__ __launch_bounds__(256) void pad_k(ushort_t* __restrict__ d1p) {
    const int img = blockIdx.x, tid = threadIdx.x;
    const uint4 z = (uint4){0, 0, 0, 0};
    uint4* b1 = (uint4*)(d1p + (size_t)img * 1065024);   // 129*129*64 elems
    for (int i = tid; i < 1032; i += 256) b1[132096 + i] = z;   // row 128
    for (int i = tid; i < 1024; i += 256) {                     // col 128
        int r = i >> 3, u = i & 7;
        b1[(r * 129 + 128) * 8 + u] = z;
    }
}

// ---------------- conv1 MFMA: x NCHW fp32 -> a1 [B,128,128,32] (interleaved)
__global__ __launch_bounds__(256, 4) void conv1_k(const float* __restrict__ x,
        const ushort_t* __restrict__ wt, const float* __restrict__ bias,
        ushort_t* __restrict__ a1) {
    const int by = blockIdx.y, b = by >> 7, oh = by & 127;
    const int tid = threadIdx.x;
    __shared__ __align__(16) ushort_t sX[9 * 264];   // [ci*3+kh][iw+1 (258 used)]
    __shared__ int sOff[32];
    for (int i = tid; i < 9 * 264 / 2; i += 256) ((unsigned*)sX)[i] = 0u;
    if (tid < 32) {
        int k = tid, off = 0;
        if (k < 27) { int ci = k / 9, r9 = k % 9, kh = r9 / 3, kw = r9 % 3;
                      off = (ci * 3 + kh) * 264 + kw; }
        sOff[tid] = off;
    }
    __syncthreads();
    #pragma unroll
    for (int it = 0; it < 9; ++it) {
        int slot = it * 256 + tid;                  // 2304 = 3ci * 3kh * 256iw
        int ci = slot / 768, r = slot % 768, kh = r >> 8, iw = r & 255;
        int ih = 2 * oh + kh - 1;
        float v = ((unsigned)ih < 256u) ? x[(long)(b * 3 + ci) * 65536 + ih * 256 + iw] : 0.f;
        sX[(ci * 3 + kh) * 264 + iw + 1] = f2bf(v);
    }
    __syncthreads();
    const int lane = tid & 63, wave = tid >> 6, q = lane >> 4, n16 = lane & 15;
    bf16x8 Bw[2];
    #pragma unroll
    for (int u = 0; u < 2; ++u)
        Bw[u] = *(const bf16x8*)(wt + (u * 16 + n16) * 32 + q * 8);
    f32x4 acc[2][2];
    #pragma unroll
    for (int u = 0; u < 2; ++u) {
        float bz = bias[u * 16 + n16];
        acc[0][u] = (f32x4){bz, bz, bz, bz};
        acc[1][u] = (f32x4){bz, bz, bz, bz};
    }
    #pragma unroll
    for (int mf = 0; mf < 2; ++mf) {
        const int m2 = 2 * (wave * 32 + mf * 16 + n16);
        ushort_t av[8];
        #pragma unroll
        for (int j = 0; j < 8; ++j) {
            int k = q * 8 + j;
            av[j] = (k < 27) ? sX[sOff[k] + m2] : (ushort_t)0;
        }
        bf16x8 A = *(bf16x8*)av;
        #pragma unroll
        for (int u = 0; u < 2; ++u)
            acc[mf][u] = __builtin_amdgcn_mfma_f32_16x16x32_bf16(A, Bw[u], acc[mf][u], 0, 0, 0);
    }
    #pragma unroll
    for (int mf = 0; mf < 2; ++mf)
        #pragma unroll
        for (int r = 0; r < 4; ++r) {
            int ow = wave * 32 + mf * 16 + q * 4 + r;
            *(unsigned*)(a1 + ((long)(b * 128 + oh) * 128 + ow) * 32 + n16 * 2) =
                pack2r(acc[mf][0][r], acc[mf][1][r]);
        }
}

// ---------------- conv2 MFMA: a1 -> a2 [B,64,64,64] (interleaved) -----------
__global__ __launch_bounds__(256, 4) void conv2_k(const ushort_t* __restrict__ a1,
        const ushort_t* __restrict__ wt, const float* __restrict__ bias,
        ushort_t* __restrict__ a2) {
    const int by = blockIdx.y, b = by >> 6, oh = by & 63;
    const int tid = threadIdx.x;
    // parity-split: [kh3][p2][c66][ci32 pad40]
    __shared__ __align__(16) ushort_t sA[3 * 2 * 66 * 40];
    uint4* z4 = (uint4*)sA;
    #pragma unroll
    for (int it = 0; it < 8; ++it) {
        int slot = it * 256 + tid;
        if (slot < 1980) z4[slot] = (uint4){0, 0, 0, 0};
    }
    __syncthreads();
    #pragma unroll
    for (int it = 0; it < 6; ++it) {
        int slot = it * 256 + tid;                    // 1536 = 3kh*128iw*4
        if (slot < 1536) {
            int kh = slot >> 9, rem = slot & 511, iw = rem >> 2, ci8 = (rem & 3) << 3;
            int ih = 2 * oh + kh - 1;
            if ((unsigned)ih < 128u) {
                uint4 v = *(const uint4*)(a1 + ((long)(b * 128 + ih) * 128 + iw) * 32 + ci8);
                int idx = iw + 2, p = idx & 1, c = idx >> 1;
                *(uint4*)&sA[((kh * 2 + p) * 66 + c) * 40 + ci8] = v;
            }
        }
    }
    __syncthreads();
    const int lane = tid & 63, wave = tid >> 6, q = lane >> 4, n16 = lane & 15;
    f32x4 acc[4];
    #pragma unroll
    for (int u = 0; u < 4; ++u) {
        float bz = bias[u * 16 + n16];
        acc[u] = (f32x4){bz, bz, bz, bz};
    }
    const int ow = wave * 16 + n16;   // A row (m)
    #pragma unroll
    for (int t = 0; t < 9; ++t) {
        const int kh = t / 3, kw = t % 3;
        const int p = (kw == 1) ? 0 : 1;
        const int c = (kw == 0) ? ow : ow + 1;
        bf16x8 A = *(bf16x8*)&sA[((kh * 2 + p) * 66 + c) * 40 + q * 8];
        #pragma unroll
        for (int u = 0; u < 4; ++u) {
            bf16x8 B = *(const bf16x8*)(wt + 1024 + t * 2048 + (u * 16 + n16) * 32 + q * 8);
            acc[u] = __builtin_amdgcn_mfma_f32_16x16x32_bf16(A, B, acc[u], 0, 0, 0);
        }
    }
    #pragma unroll
    for (int r = 0; r < 4; ++r) {
        int owo = wave * 16 + q * 4 + r;
        uint2 pk;
        pk.x = pack2r(acc[0][r], acc[1][r]);
        pk.y = pack2r(acc[2][r], acc[3][r]);
        *(uint2*)(a2 + ((long)(b * 64 + oh) * 64 + owo) * 64 + n16 * 4) = pk;
    }
}

// ---------------- conv3 (1x1) + VQ + loss, 2 px/thread ----------------------
__global__ __launch_bounds__(256) void conv3_vq_k(const ushort_t* __restrict__ a2,
        const float* __restrict__ w3, const float* __restrict__ b3,
        const float* __restrict__ cb, const float* __restrict__ cn,
        ushort_t* __restrict__ e, float* __restrict__ acc) {
    const int base = blockIdx.x * 512 + threadIdx.x;   // px0 = base, px1 = base+256
    float z[2][16];
    #pragma unroll
    for (int p = 0; p < 2; ++p)
        #pragma unroll
        for (int d = 0; d < 16; ++d) z[p][d] = b3[d];
    #pragma unroll
    for (int p = 0; p < 2; ++p) {
        const ushort_t* arow = a2 + (long)(base + p * 256) * 64;
        #pragma unroll
        for (int c8 = 0; c8 < 8; ++c8) {
            uint4 raw = *(const uint4*)(arow + c8 * 8);
            ushort_t us[8];
            *(uint4*)us = raw;
            #pragma unroll
            for (int j = 0; j < 8; ++j) {
                int m = c8 * 8 + j;
                int lci = ((m & 3) << 4) | (m >> 2);          // l4
                float a = bf2f(us[j]);
                #pragma unroll
                for (int d = 0; d < 16; ++d)
                    z[p][d] = fmaf(a, w3[d * 64 + lci], z[p][d]);
            }
        }
    }
    const float4* cb4 = (const float4*)cb;
    float best0 = 1e30f, best1 = 1e30f; int bi0 = 0, bi1 = 0;
    for (int k = 0; k < 512; ++k) {
        float4 c0 = cb4[k * 4 + 0], c1 = cb4[k * 4 + 1];
        float4 c2 = cb4[k * 4 + 2], c3 = cb4[k * 4 + 3];
        float nk = cn[k];
        float d0 = z[0][0]*c0.x + z[0][1]*c0.y + z[0][2]*c0.z + z[0][3]*c0.w
                 + z[0][4]*c1.x + z[0][5]*c1.y + z[0][6]*c1.z + z[0][7]*c1.w
                 + z[0][8]*c2.x + z[0][9]*c2.y + z[0][10]*c2.z + z[0][11]*c2.w
                 + z[0][12]*c3.x + z[0][13]*c3.y + z[0][14]*c3.z + z[0][15]*c3.w;
        float d1 = z[1][0]*c0.x + z[1][1]*c0.y + z[1][2]*c0.z + z[1][3]*c0.w
                 + z[1][4]*c1.x + z[1][5]*c1.y + z[1][6]*c1.z + z[1][7]*c1.w
                 + z[1][8]*c2.x + z[1][9]*c2.y + z[1][10]*c2.z + z[1][11]*c2.w
                 + z[1][12]*c3.x + z[1][13]*c3.y + z[1][14]*c3.z + z[1][15]*c3.w;
        float dist0 = nk - 2.f * d0, dist1 = nk - 2.f * d1;
        if (dist0 < best0) { best0 = dist0; bi0 = k; }
        if (dist1 < best1) { best1 = dist1; bi1 = k; }
    }
    float lsum = 0.f;
    #pragma unroll
    for (int d = 0; d < 16; ++d) {
        float q0 = cb[bi0 * 16 + d], q1 = cb[bi1 * 16 + d];
        float f0 = q0 - z[0][d], f1 = q1 - z[1][d];
        lsum += f0 * f0 + f1 * f1;
        e[(long)base * 16 + d] = f2bf(q0);
        e[(long)(base + 256) * 16 + d] = f2bf(q1);
    }
    #pragma unroll
    for (int off = 32; off > 0; off >>= 1) lsum += __shfl_down(lsum, off, 64);
    if ((threadIdx.x & 63) == 0) atomicAdd(&acc[0], lsum);
}

// ---------------- dec1 MFMA: e -> d1p [B,129,129,64] (interleaved) ----------
__global__ __launch_bounds__(256, 4) void dec1_k(const ushort_t* __restrict__ e,
        const ushort_t* __restrict__ wt, const float* __restrict__ bias,
        ushort_t* __restrict__ d1p) {
    const int by = blockIdx.y, b = by >> 6, i = by & 63;
    const int tid = threadIdx.x;
    __shared__ __align__(16) ushort_t sE[2 * 66 * 24];  // [dh2][j66][ci16 pad24]
    uint4* z4 = (uint4*)sE;
    #pragma unroll
    for (int it = 0; it < 2; ++it) {
        int slot = it * 256 + tid;
        if (slot < 396) z4[slot] = (uint4){0, 0, 0, 0};
    }
    __syncthreads();
    {
        int dh = tid >> 7, rem = tid & 127, j = rem >> 1, ci8 = (rem & 1) * 8;
        if (i + dh < 64) {
            uint4 v = *(const uint4*)(e + ((long)((b * 64 + i + dh) * 64 + j)) * 16 + ci8);
            *(uint4*)&sE[(dh * 66 + j) * 24 + ci8] = v;
        }
    }
    __syncthreads();
    const int lane = tid & 63, wave = tid >> 6, q = lane >> 4, n16 = lane & 15;
    f32x4 acc[4][4];   // [class ph*2+pw][ntile]
    #pragma unroll
    for (int u = 0; u < 4; ++u) {
        float bz = bias[u * 16 + n16];
        #pragma unroll
        for (int c = 0; c < 4; ++c) acc[c][u] = (f32x4){bz, bz, bz, bz};
    }
    const int jl = wave * 16 + n16;
    #pragma unroll
    for (int t = 0; t < 9; ++t) {
        const int kh = t / 3, kw = t % 3;
        const int dh = (kh == 0) ? 1 : 0, dw = (kw == 0) ? 1 : 0;
        const int cls = ((kh != 1) ? 2 : 0) | ((kw != 1) ? 1 : 0);
        bf16x8 A = *(bf16x8*)&sE[(dh * 66 + jl + dw) * 24 + (q & 1) * 8];
        #pragma unroll
        for (int u = 0; u < 4; ++u) {
            bf16x8 B = *(const bf16x8*)(wt + 19456 + t * 2048 + (u * 16 + n16) * 32 + q * 8);
            acc[cls][u] = __builtin_amdgcn_mfma_f32_16x16x32_bf16(A, B, acc[cls][u], 0, 0, 0);
        }
    }
    #pragma unroll
    for (int ph = 0; ph < 2; ++ph)
        #pragma unroll
        for (int pw = 0; pw < 2; ++pw)
            #pragma unroll
            for (int r = 0; r < 4; ++r) {
                int oh = 2 * i + ph;
                int ow = 2 * (wave * 16 + q * 4 + r) + pw;
                uint2 pk;
                pk.x = pack2r(acc[ph * 2 + pw][0][r], acc[ph * 2 + pw][1][r]);
                pk.y = pack2r(acc[ph * 2 + pw][2][r], acc[ph * 2 + pw][3][r]);
                *(uint2*)(d1p + (size_t)b * 1065024 + ((long)oh * 129 + ow) * 64 + n16 * 4) = pk;
            }
}

// ---------------- dec23: fused convT(64->32,s2) + conv(32->3) + MSE ---------
// Block: output rows 4*i4..4*i4+3, cols j0..j0+127 (j0 = bx*128).
// Stage 1: d2 rows 4i4-1..4i4+4, cols j0-1..j0+128, 32ch -> LDS tile sT
//          (from d1p rows 2i4-1..2i4+3; class-skip avoids unstored halo rows).
//          Accumulators split by kc: 16 independent chains -> B loads pipeline.
// Stage 2: per wave, one output row from sT (flipped-W conv) + fused MSE.
__global__ __launch_bounds__(256, 3) void dec23_k(const ushort_t* __restrict__ d1p,
        const ushort_t* __restrict__ wt, const float* __restrict__ db2,
        const float* __restrict__ db3, const float* __restrict__ x,
        float* __restrict__ acc) {
    const int bx = blockIdx.x, by = blockIdx.y;
    const int b = by >> 6, i4 = by & 63;
    const int j0 = bx << 7;
    const int tid = threadIdx.x;
    const int lane = tid & 63, wave = tid >> 6, q = lane >> 4, n16 = lane & 15;

    __shared__ __align__(16) ushort_t sT[6 * 132 * 32];   // [R'6][c'132][ch32] 50688 B
    uint4* z4 = (uint4*)sT;
    #pragma unroll
    for (int it = 0; it < 13; ++it) {
        int s = it * 256 + tid;
        if (s < 3168) z4[s] = (uint4){0, 0, 0, 0};
    }
    __syncthreads();

    // ---- stage 1: dec2 into sT ----
    const int bb0 = (j0 >> 1) - 1;
    const ushort_t* dbase = d1p + (size_t)b * 1065024;
    for (int s = 0; s < 5; ++s) {
        const int aidx = (wave + s) & 3;
        const int a = 2 * i4 + aidx - 1;
        const int bt = s;
        const int bcol = bb0 + bt * 16 + n16;
        bf16x8 A[2][2][2];   // [kc][dh][dw]
        #pragma unroll
        for (int dh = 0; dh < 2; ++dh) {
            int row = a + dh;
            bool rok = (unsigned)row <= 128u;
            int rowc = rok ? row : 0;
            #pragma unroll
            for (int dw = 0; dw < 2; ++dw) {
                int col = bcol + dw;
                bool cok = (unsigned)col <= 128u;
                int colc = cok ? col : 0;
                const ushort_t* p = dbase + ((long)rowc * 129 + colc) * 64;
                #pragma unroll
                for (int kc = 0; kc < 2; ++kc) {
                    bf16x8 v = *(const bf16x8*)(p + kc * 32 + q * 8);
                    if (!(rok && cok)) v = (bf16x8){0, 0, 0, 0, 0, 0, 0, 0};
                    A[kc][dh][dw] = v;
                }
            }
        }
        f32x4 acc2[4][2][2];   // [cls][u][kc] — kc-split: 16 independent chains
        #pragma unroll
        for (int u = 0; u < 2; ++u) {
            float bz = db2[u * 16 + n16];
            #pragma unroll
            for (int c = 0; c < 4; ++c) {
                acc2[c][u][0] = (f32x4){bz, bz, bz, bz};
                acc2[c][u][1] = (f32x4){0.f, 0.f, 0.f, 0.f};
            }
        }
        const bool skip0 = (aidx == 0);   // d2 row 2a+0 not in tile
        const bool skip1 = (aidx == 3);   // d2 row 2a+1 not in tile
#define MF23(cls, kh, kw, dh, dw)                                                   \
        _Pragma("unroll")                                                           \
        for (int kc = 0; kc < 2; ++kc)                                              \
            _Pragma("unroll")                                                       \
            for (int u = 0; u < 2; ++u)                                             \
                acc2[cls][u][kc] = __builtin_amdgcn_mfma_f32_16x16x32_bf16(         \
                    A[kc][dh][dw],                                                  \
                    *(const bf16x8*)(wt + 37888 + ((kh) * 3 + (kw)) * 2048 +        \
                                     kc * 1024 + (u * 16 + n16) * 32 + q * 8),      \
                    acc2[cls][u][kc], 0, 0, 0);
        if (!skip0) {
            MF23(0, 1, 1, 0, 0)
            MF23(1, 1, 0, 0, 1)  MF23(1, 1, 2, 0, 0)
        }
        if (!skip1) {
            MF23(2, 0, 1, 1, 0)  MF23(2, 2, 1, 0, 0)
            MF23(3, 0, 0, 1, 1)  MF23(3, 0, 2, 1, 0)  MF23(3, 2, 0, 0, 1)  MF23(3, 2, 2, 0, 0)
        }
#undef MF23
        #pragma unroll
        for (int cls = 0; cls < 4; ++cls) {
            int ph = cls >> 1, pw = cls & 1;
            if ((ph == 0 && skip0) || (ph == 1 && skip1)) continue;
            int R = 2 * a + ph;
            if ((unsigned)R >= 256u) continue;           // image-edge rows stay 0
            int Rp = R - 4 * i4 + 1;                     // in [0,5]
            #pragma unroll
            for (int r = 0; r < 4; ++r) {
                int cg = 2 * (bb0 + bt * 16 + q * 4 + r) + pw;   // global d2 col
                int cp = 2 * (bt * 16 + q * 4 + r) + pw - 1;     // tile col
                if ((unsigned)cg < 256u && (unsigned)cp < 130u) {
                    *(unsigned*)&sT[Rp * 4224 + cp * 32 + n16 * 2] =
                        pack2r(acc2[cls][0][0][r] + acc2[cls][0][1][r],
                               acc2[cls][1][0][r] + acc2[cls][1][1][r]);
                }
            }
        }
    }
    __syncthreads();

    // ---- stage 2: dec3 conv + MSE (wave -> row oh, cols j0..j0+127) ----
    bf16x8 Bw[9];
    #pragma unroll
    for (int t = 0; t < 9; ++t)
        Bw[t] = *(const bf16x8*)(wt + 56320 + t * 512 + n16 * 32 + q * 8);
    float bz3 = (n16 < 3) ? db3[n16] : 0.f;
    f32x4 a4[8];
    #pragma unroll
    for (int mf = 0; mf < 8; ++mf) a4[mf] = (f32x4){bz3, bz3, bz3, bz3};
    const int oh = 4 * i4 + wave;
    #pragma unroll
    for (int kh = 0; kh < 3; ++kh) {
        const ushort_t* srow = &sT[(wave + kh) * 4224];
        #pragma unroll
        for (int mf = 0; mf < 8; ++mf) {
            #pragma unroll
            for (int kw = 0; kw < 3; ++kw) {
                bf16x8 A = *(const bf16x8*)(srow + (mf * 16 + n16 + kw) * 32 + q * 8);
                a4[mf] = __builtin_amdgcn_mfma_f32_16x16x32_bf16(A, Bw[kh * 3 + kw], a4[mf], 0, 0, 0);
            }
        }
    }
    float lsum = 0.f;
    if (n16 < 3) {
        const float* xrow = x + ((long)(b * 3 + n16) * 256 + oh) * 256 + j0;
        #pragma unroll
        for (int mf = 0; mf < 8; ++mf)
            #pragma unroll
            for (int r = 0; r < 4; ++r) {
                int ow = mf * 16 + q * 4 + r;
                float df = a4[mf][r] - xrow[ow];
                lsum += df * df;
            }
    }
    #pragma unroll
    for (int off = 32; off > 0; off >>= 1) lsum += __shfl_down(lsum, off, 64);
    if (lane == 0) atomicAdd(&acc[1], lsum);
}

__global__ void finalize_k(const float* __restrict__ acc, float* __restrict__ out) {
    if (threadIdx.x == 0) {
        float eq  = 1.25f * acc[0] / 4194304.f;     // 262144 px * 16 d
        float mse = acc[1] / 12582912.f;            // 64 * 3 * 256 * 256
        out[0] = eq;
        out[1] = mse;
        out[2] = mse;
    }
}

extern "C" void kernel_launch(void* const* d_in, const int* in_sizes, int n_in,
                              void* d_out, int out_size, void* d_ws, size_t ws_size,
                              hipStream_t stream) {
    (void)in_sizes; (void)n_in; (void)out_size;
    const float* x   = (const float*)d_in[0];
    const float* ew1 = (const float*)d_in[1];
    const float* eb1 = (const float*)d_in[2];
    const float* ew2 = (const float*)d_in[3];
    const float* eb2 = (const float*)d_in[4];
    const float* ew3 = (const float*)d_in[5];
    const float* eb3 = (const float*)d_in[6];
    const float* cb  = (const float*)d_in[7];
    const float* dw1 = (const float*)d_in[8];
    const float* db1 = (const float*)d_in[9];
    const float* dw2 = (const float*)d_in[10];
    const float* db2 = (const float*)d_in[11];
    const float* dw3 = (const float*)d_in[12];
    const float* db3 = (const float*)d_in[13];
    float* out = (float*)d_out;

    // per-image bytes: e 131072 + max(enc a1+a2 = 1572864, dec d1p 2130048)
    // need(C) = 256(acc) + 131072(wbuf) + C*2261120   (C=64 -> 144.8 MB)
    int C = 64;
    while (C > 1 && (size_t)131328 + (size_t)C * 2261120UL > ws_size) C >>= 1;

    char* base = (char*)d_ws;
    float*    acc = (float*)base;
    ushort_t* wt  = (ushort_t*)(base + 256);
    float*    cn  = (float*)(base + 256 + 121856);
    ushort_t* e   = (ushort_t*)(base + 131328);
    char*     rgn = base + 131328 + (size_t)C * 131072UL;
    ushort_t* a1  = (ushort_t*)rgn;
    ushort_t* a2  = (ushort_t*)(rgn + (size_t)C * 1048576UL);
    ushort_t* d1p = (ushort_t*)rgn;                          // reuse (a1/a2 dead)

    zero_k<<<1, 64, 0, stream>>>(acc);
    prep_k<<<240, 256, 0, stream>>>(ew1, ew2, dw1, dw2, dw3, cb, wt, cn);

    for (int b0 = 0; b0 < 64; b0 += C) {
        const float* xc = x + (size_t)b0 * 196608UL;
        conv1_k   <<<dim3(1, C * 128), 256, 0, stream>>>(xc,  wt, eb1, a1);
        conv2_k   <<<dim3(1, C * 64),  256, 0, stream>>>(a1,  wt, eb2, a2);
        conv3_vq_k<<<dim3(C * 8),      256, 0, stream>>>(a2,  ew3, eb3, cb, cn, e, acc);
        pad_k     <<<dim3(C),          256, 0, stream>>>(d1p);
        dec1_k    <<<dim3(1, C * 64),  256, 0, stream>>>(e,   wt, db1, d1p);
        dec23_k   <<<dim3(2, C * 64),  256, 0, stream>>>(d1p, wt, db2, db3, xc, acc);
    }
    finalize_k<<<1, 64, 0, stream>>>(acc, out);
}